// Round 9
// baseline (168.756 us; speedup 1.0000x reference)
//
#include <hip/hip_runtime.h>
#include <stdint.h>

typedef __bf16 bf16;
typedef __bf16 bf16x8 __attribute__((ext_vector_type(8)));
typedef __bf16 bf16x4 __attribute__((ext_vector_type(4)));
typedef float f32x4 __attribute__((ext_vector_type(4)));

__device__ inline void gload_lds16(const void* g, void* l) {
  __builtin_amdgcn_global_load_lds(
      (__attribute__((address_space(1))) void*)g,
      (__attribute__((address_space(3))) void*)l, 16, 0, 0);
}

// ---------------- fused fp32 -> bf16 conversion (x + 3 weights) ----------------
__global__ __launch_bounds__(256) void cvt_all(
    const float* __restrict__ x, const float* __restrict__ wq,
    const float* __restrict__ wk, const float* __restrict__ wv,
    bf16* __restrict__ xb, bf16* __restrict__ Wb) {
  const int NX = 2097152;
  const int NW = 262144;
  int i = blockIdx.x * 256 + threadIdx.x;
  const int stride = gridDim.x * 256;
  for (int p = i; p < NX + 3 * NW; p += stride) {
    const float* src; bf16* dst; int off;
    if (p < NX) { src = x; dst = xb; off = p; }
    else {
      int q = p - NX; int w = q >> 18; off = q & (NW - 1);
      src = (w == 0) ? wq : ((w == 1) ? wk : wv);
      dst = Wb + (long)w * 1048576;
    }
    float4 v = ((const float4*)src)[off];
    bf16x4 o;
    o[0] = (bf16)v.x; o[1] = (bf16)v.y; o[2] = (bf16)v.z; o[3] = (bf16)v.w;
    ((bf16x4*)dst)[off] = o;
  }
}

// =====================================================================
// projW: QKV projection, C[xrow, wrow] = xb · Wb^T.
// M=8192 (xrows), N=3072 (wrows) -> BM=256, BN=384 -> grid 8x32 = 256 EXACT.
// BK=32, 512 threads (8 waves 2Mx4N), wave-tile 128x96, B-frag cache (6),
// 2 phases/tile (24 MFMA each), LDS 2x(A 16K + B 24K) = 80K.
// Counted vmcnt(5): tile t's data staged at t-2.P2 (A-rd0+B) / t-1.P1 (A-rd1),
// drained at t.P1 -> 2.5 phases slack.  Single (post-MFMA) barrier per phase.
// Swizzled regions: A (256-row) == gemm8 A pattern; B (384-row) == projT A
// pattern (both 0-conflict verified r2-r8).
// Epilogue: wrow<2048 -> QKbuf[xrow][wrow]; wrow>=2048 -> Vt[b][d][s] as
// bf16x4 along s (ideal WRITE traffic per r3-r6 measurements).
// =====================================================================
__global__ __launch_bounds__(512, 2) void projW(
    const bf16* __restrict__ Xg, const bf16* __restrict__ Wg,
    bf16* __restrict__ QKbuf, bf16* __restrict__ Vt)
{
  constexpr int BUFSZ = 40960;
  __shared__ alignas(16) char lds[2 * BUFSZ];
  const int tid = threadIdx.x;
  const int l = tid & 63;
  const int wv = tid >> 6;
  const int wm = wv >> 2;        // 0..1
  const int wn = wv & 3;         // 0..3
  const int fr = l & 15;
  const int kch = l >> 4;
  const int m0 = blockIdx.y * 256;   // x-row base
  const int n0 = blockIdx.x * 384;   // w-row base

  // A fragment read: + m*2048 (m=0..7; m<4 in rd0-rows, m>=4 in rd1-rows)
  const int a_rd = fr * 128 + (((wm * 4 + kch) ^ (fr & 7)) << 4);
  // B fragment read offsets per n (region base 16384, 384 rows, halves of 192)
  int b_off[6];
#pragma unroll
  for (int n = 0; n < 6; ++n) {
    const int rowbase = wn * 96 + n * 16;
    const int half = rowbase >= 192 ? 1 : 0;
    b_off[n] = 16384 + (rowbase - half * 192 + fr) * 128 +
               (((half * 4 + kch) ^ (fr & 7)) << 4);
  }

  // staging (inverse swizzle), linear gload_lds dest
  const int se = (tid & 7) ^ ((tid >> 3) & 7);
  const int s_rowA = (se >> 2) * 128 + (tid >> 3);   // + rd*64, rd=0..1
  const int s_rowB = (se >> 2) * 192 + (tid >> 3);   // + rd*64, rd=0..2
  const int s_k = (se & 3) * 8;
  const int wb16 = (tid & 448) * 16;

  f32x4 acc[8][6] = {};

  auto stageA = [&](int tile, int buf, int rd) {
    gload_lds16(Xg + (long)(m0 + s_rowA + rd * 64) * 1024 + tile * 32 + s_k,
                lds + buf * BUFSZ + rd * 8192 + wb16);
  };
  auto stageB = [&](int tile, int buf, int rd) {
    gload_lds16(Wg + (long)(n0 + s_rowB + rd * 64) * 1024 + tile * 32 + s_k,
                lds + buf * BUFSZ + 16384 + rd * 8192 + wb16);
  };

  // prologue: tile0 full -> buf0 (5); tile1 {A-rd0, B} -> buf1 (4)
  stageA(0, 0, 0); stageA(0, 0, 1);
  stageB(0, 0, 0); stageB(0, 0, 1); stageB(0, 0, 2);
  stageA(1, 1, 0);
  stageB(1, 1, 0); stageB(1, 1, 1); stageB(1, 1, 2);
  asm volatile("s_waitcnt vmcnt(4)" ::: "memory");
  __builtin_amdgcn_sched_barrier(0);
  __builtin_amdgcn_s_barrier();

  for (int t = 0; t < 32; ++t) {
    const char* buf = lds + (t & 1) * BUFSZ;
    const int t1 = min(t + 1, 31);
    const int t2 = min(t + 2, 31);
    const int nb = (t & 1) ^ 1;
    const int cur = t & 1;

    bf16x8 bfg[6], af[4];
    // P1: issue A-rd1[t+1] -> nb; drain tile-t stages; read B(6) + A m0..3
    stageA(t1, nb, 1);
    asm volatile("s_waitcnt vmcnt(5)" ::: "memory");
    __builtin_amdgcn_sched_barrier(0);
#pragma unroll
    for (int n = 0; n < 6; ++n) bfg[n] = *(const bf16x8*)(buf + b_off[n]);
#pragma unroll
    for (int m = 0; m < 4; ++m) af[m] = *(const bf16x8*)(buf + m * 2048 + a_rd);
    __builtin_amdgcn_s_setprio(1);
#pragma unroll
    for (int m = 0; m < 4; ++m)
#pragma unroll
      for (int n = 0; n < 6; ++n)
        acc[m][n] = __builtin_amdgcn_mfma_f32_16x16x32_bf16(af[m], bfg[n], acc[m][n], 0, 0, 0);
    __builtin_amdgcn_s_setprio(0);
    __builtin_amdgcn_s_barrier();
    // P2: stage A-rd0[t+2] + B[t+2] -> cur (regions consumed in P1); read A m4..7
    stageA(t2, cur, 0);
    stageB(t2, cur, 0); stageB(t2, cur, 1); stageB(t2, cur, 2);
#pragma unroll
    for (int m = 0; m < 4; ++m) af[m] = *(const bf16x8*)(buf + (4 + m) * 2048 + a_rd);
    __builtin_amdgcn_s_setprio(1);
#pragma unroll
    for (int m = 0; m < 4; ++m)
#pragma unroll
      for (int n = 0; n < 6; ++n)
        acc[4 + m][n] = __builtin_amdgcn_mfma_f32_16x16x32_bf16(af[m], bfg[n], acc[4 + m][n], 0, 0, 0);
    __builtin_amdgcn_s_setprio(0);
    __builtin_amdgcn_s_barrier();
  }
  asm volatile("s_waitcnt vmcnt(0)" ::: "memory");

  // epilogue: row = xrow, col = wrow
#pragma unroll
  for (int mf = 0; mf < 8; ++mf) {
    const int row = m0 + wm * 128 + mf * 16 + (l >> 4) * 4;
#pragma unroll
    for (int n = 0; n < 6; ++n) {
      const int col = n0 + wn * 96 + n * 16 + fr;
      if (col < 2048) {
#pragma unroll
        for (int r = 0; r < 4; ++r)
          QKbuf[(long)(row + r) * 2048 + col] = (bf16)acc[mf][n][r];
      } else {
        const int b = row >> 11;
        const int s = row & 2047;
        const int d = col - 2048;
        bf16x4 pk;
#pragma unroll
        for (int r = 0; r < 4; ++r) pk[r] = (bf16)acc[mf][n][r];
        *(bf16x4*)(Vt + (long)b * 2097152 + (long)d * 2048 + s) = pk;
      }
    }
  }
}

// =====================================================================
// gemm8: BM=256, BN=256, BK=64, 512 threads (8 waves 2Mx4N), LDS 128K,
// B-frag cache, 4 phases/tile, counted vmcnt(4).  SINGLE barrier per
// phase (post-MFMA) — waves desync within a phase so reads overlap MFMA.
// Used for QK (256 blocks, 1 round).  bf16 out with scale.
// =====================================================================
__global__ __launch_bounds__(512, 2) void gemm8(
    const bf16* __restrict__ Ag, const bf16* __restrict__ Bg,
    bf16* __restrict__ Cg,
    long lda, long ldb, long ldc,
    long sA, long sB, long sC, int K, float scale)
{
  constexpr int BUFSZ = 65536;
  __shared__ alignas(16) char lds[2 * BUFSZ];
  const int tid = threadIdx.x;
  const int l = tid & 63;
  const int wv = tid >> 6;
  const int fr = l & 15;
  const int kch = l >> 4;
  const int m0 = blockIdx.y * 256;
  const int n0 = blockIdx.x * 256;
  const bf16* Ab = Ag + (long)blockIdx.z * sA;
  const bf16* Bb = Bg + (long)blockIdx.z * sB;

  const int wm = wv >> 2;
  const int wn = wv & 3;

  const int a_rd = fr * 128 + (((wm * 4 + kch) ^ (fr & 7)) << 4);
  const int b_rd = (wn & 1) * 8192 + fr * 128 + ((((wn >> 1) * 4 + kch) ^ (fr & 7)) << 4);

  const int se = (tid & 7) ^ ((tid >> 3) & 7);
  const int s_row = (se >> 2) * 128 + (tid >> 3);
  const int s_k = (se & 3) * 8;
  const int wb16 = (tid & 448) * 16;

  const int NT = K >> 6;
  f32x4 acc[8][4] = {};

  auto stageA = [&](int tile, int kh, int buf) {
#pragma unroll
    for (int rd = 0; rd < 2; ++rd)
      gload_lds16(Ab + (long)(m0 + s_row + rd * 64) * lda + tile * 64 + kh * 32 + s_k,
                  lds + buf * BUFSZ + kh * 16384 + rd * 8192 + wb16);
  };
  auto stageB = [&](int tile, int kh, int buf) {
#pragma unroll
    for (int rd = 0; rd < 2; ++rd)
      gload_lds16(Bb + (long)(n0 + s_row + rd * 64) * ldb + tile * 64 + kh * 32 + s_k,
                  lds + buf * BUFSZ + 32768 + kh * 16384 + rd * 8192 + wb16);
  };

  stageA(0, 0, 0); stageB(0, 0, 0); stageA(0, 1, 0); stageB(0, 1, 0);
  stageA(min(1, NT - 1), 0, 1); stageB(min(1, NT - 1), 0, 1);
  asm volatile("s_waitcnt vmcnt(4)" ::: "memory");
  __builtin_amdgcn_sched_barrier(0);
  __builtin_amdgcn_s_barrier();

  for (int t = 0; t < NT; ++t) {
    const char* bufA = lds + (t & 1) * BUFSZ;
    const char* bufB = bufA + 32768;
    const int t1 = min(t + 1, NT - 1);
    const int t2 = min(t + 2, NT - 1);
    const int nb = (t & 1) ^ 1;
    const int cur = t & 1;

    bf16x8 bfg[4], af[4];
    // P1: stage A(t+1,kh1)->nb; read B kh0 + A kh0-MH0; MFMA; barrier
    stageA(t1, 1, nb);
#pragma unroll
    for (int n = 0; n < 4; ++n) bfg[n] = *(const bf16x8*)(bufB + n * 2048 + b_rd);
#pragma unroll
    for (int m = 0; m < 4; ++m) af[m] = *(const bf16x8*)(bufA + m * 2048 + a_rd);
    __builtin_amdgcn_s_setprio(1);
#pragma unroll
    for (int m = 0; m < 4; ++m)
#pragma unroll
      for (int n = 0; n < 4; ++n)
        acc[m][n] = __builtin_amdgcn_mfma_f32_16x16x32_bf16(af[m], bfg[n], acc[m][n], 0, 0, 0);
    __builtin_amdgcn_s_setprio(0);
    __builtin_amdgcn_s_barrier();
    // P2: stage B(t+1,kh1)->nb; read A kh0-MH1 (B cached); MFMA; barrier
    stageB(t1, 1, nb);
#pragma unroll
    for (int m = 0; m < 4; ++m) af[m] = *(const bf16x8*)(bufA + 8192 + m * 2048 + a_rd);
    __builtin_amdgcn_s_setprio(1);
#pragma unroll
    for (int m = 0; m < 4; ++m)
#pragma unroll
      for (int n = 0; n < 4; ++n)
        acc[4 + m][n] = __builtin_amdgcn_mfma_f32_16x16x32_bf16(af[m], bfg[n], acc[4 + m][n], 0, 0, 0);
    __builtin_amdgcn_s_setprio(0);
    __builtin_amdgcn_s_barrier();
    // P3: stage A(t+2,kh0)->cur (consumed P1/P2); read B kh1 + A kh1-MH0
    stageA(t2, 0, cur);
#pragma unroll
    for (int n = 0; n < 4; ++n) bfg[n] = *(const bf16x8*)(bufB + 16384 + n * 2048 + b_rd);
#pragma unroll
    for (int m = 0; m < 4; ++m) af[m] = *(const bf16x8*)(bufA + 16384 + m * 2048 + a_rd);
    __builtin_amdgcn_s_setprio(1);
#pragma unroll
    for (int m = 0; m < 4; ++m)
#pragma unroll
      for (int n = 0; n < 4; ++n)
        acc[m][n] = __builtin_amdgcn_mfma_f32_16x16x32_bf16(af[m], bfg[n], acc[m][n], 0, 0, 0);
    __builtin_amdgcn_s_setprio(0);
    __builtin_amdgcn_s_barrier();
    // P4: stage B(t+2,kh0)->cur; read A kh1-MH1; MFMA; vmcnt(4); barrier
    stageB(t2, 0, cur);
#pragma unroll
    for (int m = 0; m < 4; ++m) af[m] = *(const bf16x8*)(bufA + 16384 + 8192 + m * 2048 + a_rd);
    __builtin_amdgcn_s_setprio(1);
#pragma unroll
    for (int m = 0; m < 4; ++m)
#pragma unroll
      for (int n = 0; n < 4; ++n)
        acc[4 + m][n] = __builtin_amdgcn_mfma_f32_16x16x32_bf16(af[m], bfg[n], acc[4 + m][n], 0, 0, 0);
    __builtin_amdgcn_s_setprio(0);
    asm volatile("s_waitcnt vmcnt(4)" ::: "memory");
    __builtin_amdgcn_sched_barrier(0);
    __builtin_amdgcn_s_barrier();
  }
  asm volatile("s_waitcnt vmcnt(0)" ::: "memory");

#pragma unroll
  for (int mf = 0; mf < 8; ++mf) {
    const int row = m0 + wm * 128 + (mf >> 2) * 64 + (mf & 3) * 16 + (l >> 4) * 4;
#pragma unroll
    for (int n = 0; n < 4; ++n) {
      const int col = n0 + wn * 64 + n * 16 + fr;
      bf16* C = Cg + (long)blockIdx.z * sC;
#pragma unroll
      for (int r = 0; r < 4; ++r)
        C[(long)(row + r) * ldc + col] = (bf16)(acc[mf][n][r] * scale);
    }
  }
}

// =====================================================================
// gemm2h: BM=128, BN=128, BK=64, 256 threads (4 waves 2Mx2N), LDS 64K,
// 2 blocks/CU.  Single barrier per phase.  Used for PV.  fp32 out.
// =====================================================================
__global__ __launch_bounds__(256, 2) void gemm2h(
    const bf16* __restrict__ Ag, const bf16* __restrict__ Bg,
    float* __restrict__ Cg,
    long lda, long ldb, long ldc,
    long sA, long sB, long sC, int K)
{
  constexpr int BUFSZ = 32768;
  __shared__ alignas(16) char lds[2 * BUFSZ];
  const int tid = threadIdx.x;
  const int l = tid & 63;
  const int wv = tid >> 6;
  const int wm = wv >> 1, wn = wv & 1;
  const int fr = l & 15;
  const int kch = l >> 4;
  const int m0 = blockIdx.y * 128;
  const int n0 = blockIdx.x * 128;
  const bf16* Ab = Ag + (long)blockIdx.z * sA;
  const bf16* Bb = Bg + (long)blockIdx.z * sB;

  const int a_rd = fr * 128 + (((wm * 4 + kch) ^ (fr & 7)) << 4);
  const int b_rd = fr * 128 + (((wn * 4 + kch) ^ (fr & 7)) << 4);

  const int se = (tid & 7) ^ ((tid >> 3) & 7);
  const int s_row = (se >> 2) * 64 + (tid >> 3);
  const int s_k = (se & 3) * 8;
  const int wb16 = (tid >> 6) * 1024;

  const int NT = K >> 6;
  f32x4 acc[4][4] = {};

  auto stageA = [&](int tile, int kh, int buf) {
#pragma unroll
    for (int rd = 0; rd < 2; ++rd)
      gload_lds16(Ab + (long)(m0 + s_row + rd * 32) * lda + tile * 64 + kh * 32 + s_k,
                  lds + buf * BUFSZ + kh * 8192 + rd * 4096 + wb16);
  };
  auto stageB = [&](int tile, int kh, int buf) {
#pragma unroll
    for (int rd = 0; rd < 2; ++rd)
      gload_lds16(Bb + (long)(n0 + s_row + rd * 32) * ldb + tile * 64 + kh * 32 + s_k,
                  lds + buf * BUFSZ + 16384 + kh * 8192 + rd * 4096 + wb16);
  };

  stageA(0, 0, 0); stageB(0, 0, 0); stageA(0, 1, 0); stageB(0, 1, 0);
  stageA(min(1, NT - 1), 0, 1); stageB(min(1, NT - 1), 0, 1);
  asm volatile("s_waitcnt vmcnt(4)" ::: "memory");
  __builtin_amdgcn_sched_barrier(0);
  __builtin_amdgcn_s_barrier();

  for (int t = 0; t < NT; ++t) {
    const char* bufA = lds + (t & 1) * BUFSZ;
    const char* bufB = bufA + 16384;
    const int t1 = min(t + 1, NT - 1);
    const int t2 = min(t + 2, NT - 1);
    const int nb = (t & 1) ^ 1;
    const int cur = t & 1;

    bf16x8 bfg[4], af[4];
    // P1: stage(t+1,kh1)->nb; read kh0; MFMA; barrier
    stageA(t1, 1, nb); stageB(t1, 1, nb);
#pragma unroll
    for (int n = 0; n < 4; ++n) bfg[n] = *(const bf16x8*)(bufB + n * 2048 + b_rd);
#pragma unroll
    for (int m = 0; m < 4; ++m) af[m] = *(const bf16x8*)(bufA + m * 2048 + a_rd);
    __builtin_amdgcn_s_setprio(1);
#pragma unroll
    for (int m = 0; m < 4; ++m)
#pragma unroll
      for (int n = 0; n < 4; ++n)
        acc[m][n] = __builtin_amdgcn_mfma_f32_16x16x32_bf16(af[m], bfg[n], acc[m][n], 0, 0, 0);
    __builtin_amdgcn_s_setprio(0);
    __builtin_amdgcn_s_barrier();
    // P2: stage(t+2,kh0)->cur (consumed P1); read kh1; MFMA; vmcnt; barrier
    stageA(t2, 0, cur); stageB(t2, 0, cur);
#pragma unroll
    for (int n = 0; n < 4; ++n) bfg[n] = *(const bf16x8*)(bufB + 8192 + n * 2048 + b_rd);
#pragma unroll
    for (int m = 0; m < 4; ++m) af[m] = *(const bf16x8*)(bufA + 8192 + m * 2048 + a_rd);
    __builtin_amdgcn_s_setprio(1);
#pragma unroll
    for (int m = 0; m < 4; ++m)
#pragma unroll
      for (int n = 0; n < 4; ++n)
        acc[m][n] = __builtin_amdgcn_mfma_f32_16x16x32_bf16(af[m], bfg[n], acc[m][n], 0, 0, 0);
    __builtin_amdgcn_s_setprio(0);
    asm volatile("s_waitcnt vmcnt(4)" ::: "memory");
    __builtin_amdgcn_sched_barrier(0);
    __builtin_amdgcn_s_barrier();
  }
  asm volatile("s_waitcnt vmcnt(0)" ::: "memory");

#pragma unroll
  for (int mf = 0; mf < 4; ++mf) {
    const int row = m0 + wm * 64 + mf * 16 + (l >> 4) * 4;
#pragma unroll
    for (int n = 0; n < 4; ++n) {
      const int col = n0 + wn * 64 + n * 16 + fr;
      float* C = Cg + (long)blockIdx.z * sC;
#pragma unroll
      for (int r = 0; r < 4; ++r)
        C[(long)(row + r) * ldc + col] = acc[mf][n][r];
    }
  }
}

// ---------------- row softmax: bf16 scores -> bf16 P ----------------
__global__ __launch_bounds__(256) void softmax_k(const bf16* __restrict__ Sm,
                                                 bf16* __restrict__ P, int cols) {
  __shared__ float red[8];
  const long row = blockIdx.x;
  const bf16* sr = Sm + row * (long)cols;
  bf16* pr = P + row * (long)cols;
  const int t = threadIdx.x;
  bf16x8 v = *(const bf16x8*)(sr + t * 8);
  float e[8];
#pragma unroll
  for (int j = 0; j < 8; ++j) e[j] = (float)v[j];
  float m = e[0];
#pragma unroll
  for (int j = 1; j < 8; ++j) m = fmaxf(m, e[j]);
#pragma unroll
  for (int o = 32; o; o >>= 1) m = fmaxf(m, __shfl_xor(m, o));
  if ((t & 63) == 0) red[t >> 6] = m;
  __syncthreads();
  m = fmaxf(fmaxf(red[0], red[1]), fmaxf(red[2], red[3]));
  float s = 0.f;
#pragma unroll
  for (int j = 0; j < 8; ++j) { e[j] = __expf(e[j] - m); s += e[j]; }
#pragma unroll
  for (int o = 32; o; o >>= 1) s += __shfl_xor(s, o);
  if ((t & 63) == 0) red[4 + (t >> 6)] = s;
  __syncthreads();
  s = red[4] + red[5] + red[6] + red[7];
  const float inv = 1.0f / s;
  bf16x8 o8;
#pragma unroll
  for (int j = 0; j < 8; ++j) o8[j] = (bf16)(e[j] * inv);
  *(bf16x8*)(pr + t * 8) = o8;
}

extern "C" void kernel_launch(void* const* d_in, const int* in_sizes, int n_in,
                              void* d_out, int out_size, void* d_ws, size_t ws_size,
                              hipStream_t stream) {
  const float* x  = (const float*)d_in[0];
  const float* Wq = (const float*)d_in[1];
  const float* Wk = (const float*)d_in[2];
  const float* Wv = (const float*)d_in[3];
  float* out = (float*)d_out;

  // workspace (117.44 MB):
  //  [0, 33.55M)        QKbuf bf16 [8192][2048]  -> later P (softmax out)
  //  [33.55M, 50.33M)   Vt bf16 [4][1024][2048]  (written by projW epilogue)
  //  [50.33M, 83.89M)   scores bf16 [4][2048][2048]
  //     (pre-QK this region holds xb @50.33M (16.78M), Wb @67.11M (6.29M))
  char* ws = (char*)d_ws;
  bf16* QKbuf = (bf16*)(ws);
  bf16* P     = (bf16*)(ws);
  bf16* Vt    = (bf16*)(ws + 33554432);
  bf16* scb   = (bf16*)(ws + 50331648);
  bf16* xb    = (bf16*)(ws + 50331648);
  bf16* Wb    = (bf16*)(ws + 67108864);

  dim3 b256(256, 1, 1), b512(512, 1, 1);

  // 1) fused conversion: x -> xb, weights -> Wb packed [3][1024][1024]
  cvt_all<<<2048, b256, 0, stream>>>(x, Wq, Wk, Wv, xb, Wb);

  // 2) QKV proj (BM=256 x BN=384, 256 blocks exact): Q/K -> QKbuf, V^T -> Vt
  projW<<<dim3(8, 32, 1), b512, 0, stream>>>(xb, Wb, QKbuf, Vt);

  // 3) scores = Q @ K^T / 32 -> bf16 (gemm8; 256 blocks = 1 round)
  gemm8<<<dim3(8, 8, 4), b512, 0, stream>>>(
      QKbuf, QKbuf + 1024, scb, 2048, 2048, 2048,
      4194304, 4194304, 4194304, 1024, 0.03125f);

  // 4) softmax rows (bf16 in) -> bf16 P (overwrites dead QKbuf)
  softmax_k<<<8192, b256, 0, stream>>>(scb, P, 2048);

  // 5) out = P @ Vt^T (gemm2h: 512 blocks = 2/CU)
  gemm2h<<<dim3(8, 16, 4), b256, 0, stream>>>(
      P, Vt, out, 2048, 2048, 1024,
      4194304, 2097152, 2097152, 2048);
}